// Round 21
// baseline (214.526 us; speedup 1.0000x reference)
//
#include <hip/hip_runtime.h>

#define NBATCH 256
#define P 1024
#define Q 128
#define NS_LOOP 6

typedef _Float16 half8 __attribute__((ext_vector_type(8)));
typedef float f32x4 __attribute__((ext_vector_type(4)));
struct __attribute__((aligned(8))) Half4 { _Float16 x, y, z, w; };

// raw workgroup barrier: LDS visibility only, vmcnt floats across.
__device__ __forceinline__ void barrier_lds_only() {
    asm volatile("s_waitcnt lgkmcnt(0)" ::: "memory");
    __builtin_amdgcn_s_barrier();
    asm volatile("" ::: "memory");
}

// ---- swizzled fp16 machinery for ns/apply (counter-clean since r6) ----
__device__ __forceinline__ half8 frag_ld(const Half4* S, int rowbase, int slotbase, int lane) {
    const int r = rowbase + (lane & 15);
    const int g = (lane >> 4);
    const int rx = r & 15;
    const Half4 h1 = S[r * 32 + ((slotbase + g) ^ rx)];
    const Half4 h2 = S[r * 32 + ((slotbase + g + 4) ^ rx)];
    half8 v;
    v[0] = h1.x; v[1] = h1.y; v[2] = h1.z; v[3] = h1.w;
    v[4] = h2.x; v[5] = h2.y; v[6] = h2.z; v[7] = h2.w;
    return v;
}

__device__ __forceinline__ int cpos(int RB, int CB, int lane) {
    const int r = CB + (lane & 15);
    const int s = (RB >> 2) + (lane >> 4);
    return r * 32 + (s ^ (r & 15));
}

__device__ __forceinline__ f32x4 cread(const Half4* S, int p) {
    const Half4 h = S[p];
    f32x4 v;
    v[0] = (float)h.x; v[1] = (float)h.y; v[2] = (float)h.z; v[3] = (float)h.w;
    return v;
}

__device__ __forceinline__ void cwrite(Half4* S, int p, f32x4 v) {
    Half4 h;
    h.x = (_Float16)v[0]; h.y = (_Float16)v[1]; h.z = (_Float16)v[2]; h.w = (_Float16)v[3];
    S[p] = h;
}

__device__ __forceinline__ void cwrite_hl(Half4* Sh, Half4* Sl, int p, f32x4 v) {
    Half4 h, l;
    h.x = (_Float16)v[0]; h.y = (_Float16)v[1]; h.z = (_Float16)v[2]; h.w = (_Float16)v[3];
    l.x = (_Float16)(v[0] - (float)h.x);
    l.y = (_Float16)(v[1] - (float)h.y);
    l.z = (_Float16)(v[2] - (float)h.z);
    l.w = (_Float16)(v[3] - (float)h.w);
    Sh[p] = h; Sl[p] = l;
}

// ===========================================================================
// Kernel 1 (npart=4): gram, MFMA-identity transpose (r17, validated), with
// CHUNK=64 rows and ONE barrier per chunk (r20 residual diagnosed as
// phase-boundary overhead: 16 barriers/part + short bursts). 4 phases/part.
// ===========================================================================
__global__ __launch_bounds__(512) void gram_kernel4(
    const float* __restrict__ X, const float* __restrict__ G,
    const float* __restrict__ lrp, float* __restrict__ gpart,
    _Float16* __restrict__ tempH)
{
    __shared__ __align__(16) _Float16 sF[2][2][2][4096];  // [buf][win][hi/lo] = 64KB

    const int n = blockIdx.x >> 2;
    const int part = blockIdx.x & 3;
    const float lr = *lrp;
    const float* xb = X + (size_t)n * P * Q;
    const float* gb = G + (size_t)n * P * Q;
    _Float16* th = tempH + (size_t)n * P * Q;

    const int tid = threadIdx.x;
    const int lane = tid & 63;
    const int wid = tid >> 6;
    const int rr = lane & 15;
    const int g = lane >> 4;
    const int RB = wid * 16;
    const int cq = wid * 4 + g;

    half8 ifrag;
#pragma unroll
    for (int j = 0; j < 8; ++j) ifrag[j] = (_Float16)0.0f;
#pragma unroll
    for (int j = 0; j < 4; ++j)
        if ((rr >> 2) == g && (rr & 3) == j) ifrag[j] = (_Float16)1.0f;

    const f32x4 zero4 = {0.0f, 0.0f, 0.0f, 0.0f};
    f32x4 acc[8];
#pragma unroll
    for (int fj = 0; fj < 8; ++fj) acc[fj] = zero4;

    const int ps = part * 256;   // 4 chunks of 64 rows

    auto g_issue = [&](int pbase, float4* d) {
#pragma unroll
        for (int t = 0; t < 4; ++t) {
            d[2 * t]     = ((const float4*)(xb + (size_t)(pbase + 16 * t + rr) * Q))[cq];
            d[2 * t + 1] = ((const float4*)(gb + (size_t)(pbase + 16 * t + rr) * Q))[cq];
        }
    };
    // one K=32 window: d = {x0,g0,x1,g1} for rows pbase+rr, pbase+16+rr
    auto w_half = [&](const float4* d, int buf, int win, int pbase) {
        const float t0[4] = {d[0].x - lr * d[1].x, d[0].y - lr * d[1].y,
                             d[0].z - lr * d[1].z, d[0].w - lr * d[1].w};
        const float t1[4] = {d[2].x - lr * d[3].x, d[2].y - lr * d[3].y,
                             d[2].z - lr * d[3].z, d[2].w - lr * d[3].w};
        Half4 h0, h1;
        h0.x = (_Float16)t0[0]; h0.y = (_Float16)t0[1];
        h0.z = (_Float16)t0[2]; h0.w = (_Float16)t0[3];
        h1.x = (_Float16)t1[0]; h1.y = (_Float16)t1[1];
        h1.z = (_Float16)t1[2]; h1.w = (_Float16)t1[3];
        *(Half4*)(th + (size_t)(pbase + rr) * Q + 4 * cq) = h0;
        *(Half4*)(th + (size_t)(pbase + 16 + rr) * Q + 4 * cq) = h1;
        half8 thi0, tlo0, thi1, tlo1;
#pragma unroll
        for (int j = 0; j < 8; ++j) { thi0[j] = (_Float16)0.0f; tlo0[j] = (_Float16)0.0f;
                                      thi1[j] = (_Float16)0.0f; tlo1[j] = (_Float16)0.0f; }
#pragma unroll
        for (int j = 0; j < 4; ++j) {
            thi0[j] = (_Float16)t0[j]; tlo0[j] = (_Float16)(t0[j] - (float)thi0[j]);
            thi1[j] = (_Float16)t1[j]; tlo1[j] = (_Float16)(t1[j] - (float)thi1[j]);
        }
        f32x4 c0 = __builtin_amdgcn_mfma_f32_16x16x32_f16(thi0, ifrag, zero4, 0, 0, 0);
        c0 = __builtin_amdgcn_mfma_f32_16x16x32_f16(tlo0, ifrag, c0, 0, 0, 0);
        f32x4 c1 = __builtin_amdgcn_mfma_f32_16x16x32_f16(thi1, ifrag, zero4, 0, 0, 0);
        c1 = __builtin_amdgcn_mfma_f32_16x16x32_f16(tlo1, ifrag, c1, 0, 0, 0);
        half8 ah, al;
#pragma unroll
        for (int j = 0; j < 4; ++j) {
            ah[j] = (_Float16)c0[j];     al[j] = (_Float16)(c0[j] - (float)ah[j]);
            ah[4 + j] = (_Float16)c1[j]; al[4 + j] = (_Float16)(c1[j] - (float)ah[4 + j]);
        }
        *(half8*)(&sF[buf][win][0][((wid << 6) + lane) * 8]) = ah;
        *(half8*)(&sF[buf][win][1][((wid << 6) + lane) * 8]) = al;
    };
    auto w_phase = [&](const float4* d, int buf, int pbase) {
        w_half(d, buf, 0, pbase);
        w_half(d + 4, buf, 1, pbase + 32);
    };
    auto r_phase = [&](int buf) {
#pragma unroll
        for (int win = 0; win < 2; ++win) {
            const half8 ahi = *(const half8*)(&sF[buf][win][0][((wid << 6) + lane) * 8]);
            const half8 alo = *(const half8*)(&sF[buf][win][1][((wid << 6) + lane) * 8]);
#pragma unroll
            for (int fj = 0; fj < 8; ++fj) {
                const half8 bhi = *(const half8*)(&sF[buf][win][0][((fj << 6) + lane) * 8]);
                const half8 blo = *(const half8*)(&sF[buf][win][1][((fj << 6) + lane) * 8]);
                acc[fj] = __builtin_amdgcn_mfma_f32_16x16x32_f16(ahi, bhi, acc[fj], 0, 0, 0);
                acc[fj] = __builtin_amdgcn_mfma_f32_16x16x32_f16(ahi, blo, acc[fj], 0, 0, 0);
                acc[fj] = __builtin_amdgcn_mfma_f32_16x16x32_f16(alo, bhi, acc[fj], 0, 0, 0);
            }
        }
    };

    float4 tE[8], tO[8];
    g_issue(ps + 0 * 64, tE);
    w_phase(tE, 0, ps + 0 * 64);
    g_issue(ps + 1 * 64, tO);

    // chunk 0
    barrier_lds_only();
    g_issue(ps + 2 * 64, tE);
    r_phase(0);
    w_phase(tO, 1, ps + 1 * 64);
    // chunk 1
    barrier_lds_only();
    g_issue(ps + 3 * 64, tO);
    r_phase(1);
    w_phase(tE, 0, ps + 2 * 64);
    // chunk 2
    barrier_lds_only();
    r_phase(0);
    w_phase(tO, 1, ps + 3 * 64);
    // chunk 3
    barrier_lds_only();
    r_phase(1);

    float* gm = gpart + ((size_t)n * 4 + part) * Q * Q;
    const int m0 = (lane >> 4) * 4;
    const int nn = lane & 15;
#pragma unroll
    for (int fj = 0; fj < 8; ++fj) {
#pragma unroll
        for (int j = 0; j < 4; ++j) {
            gm[(size_t)(RB + m0 + j) * Q + fj * 16 + nn] = acc[fj][j];
        }
    }
}

// ---- fallback gram (npart=1, no tempH): r18 plain path, 32-row chunks ----
__global__ __launch_bounds__(512) void gram_kernel1(
    const float* __restrict__ X, const float* __restrict__ G,
    const float* __restrict__ lrp, float* __restrict__ gpart)
{
    __shared__ __align__(16) _Float16 sF[2][2][4096];

    const int n = blockIdx.x;
    const float lr = *lrp;
    const float* xb = X + (size_t)n * P * Q;
    const float* gb = G + (size_t)n * P * Q;

    const int tid = threadIdx.x;
    const int lane = tid & 63;
    const int wid = tid >> 6;
    const int rr = lane & 15;
    const int g = lane >> 4;
    const int RB = wid * 16;
    const int cq = wid * 4 + g;

    half8 ifrag;
#pragma unroll
    for (int j = 0; j < 8; ++j) ifrag[j] = (_Float16)0.0f;
#pragma unroll
    for (int j = 0; j < 4; ++j)
        if ((rr >> 2) == g && (rr & 3) == j) ifrag[j] = (_Float16)1.0f;

    const f32x4 zero4 = {0.0f, 0.0f, 0.0f, 0.0f};
    f32x4 acc[8];
#pragma unroll
    for (int fj = 0; fj < 8; ++fj) acc[fj] = zero4;

    auto g_issue = [&](int pbase, float4* d) {
        d[0] = ((const float4*)(xb + (size_t)(pbase + rr) * Q))[cq];
        d[1] = ((const float4*)(gb + (size_t)(pbase + rr) * Q))[cq];
        d[2] = ((const float4*)(xb + (size_t)(pbase + 16 + rr) * Q))[cq];
        d[3] = ((const float4*)(gb + (size_t)(pbase + 16 + rr) * Q))[cq];
    };
    auto w_phase = [&](const float4* d, int buf) {
        const float t0[4] = {d[0].x - lr * d[1].x, d[0].y - lr * d[1].y,
                             d[0].z - lr * d[1].z, d[0].w - lr * d[1].w};
        const float t1[4] = {d[2].x - lr * d[3].x, d[2].y - lr * d[3].y,
                             d[2].z - lr * d[3].z, d[2].w - lr * d[3].w};
        half8 thi0, tlo0, thi1, tlo1;
#pragma unroll
        for (int j = 0; j < 8; ++j) { thi0[j] = (_Float16)0.0f; tlo0[j] = (_Float16)0.0f;
                                      thi1[j] = (_Float16)0.0f; tlo1[j] = (_Float16)0.0f; }
#pragma unroll
        for (int j = 0; j < 4; ++j) {
            thi0[j] = (_Float16)t0[j]; tlo0[j] = (_Float16)(t0[j] - (float)thi0[j]);
            thi1[j] = (_Float16)t1[j]; tlo1[j] = (_Float16)(t1[j] - (float)thi1[j]);
        }
        f32x4 c0 = __builtin_amdgcn_mfma_f32_16x16x32_f16(thi0, ifrag, zero4, 0, 0, 0);
        c0 = __builtin_amdgcn_mfma_f32_16x16x32_f16(tlo0, ifrag, c0, 0, 0, 0);
        f32x4 c1 = __builtin_amdgcn_mfma_f32_16x16x32_f16(thi1, ifrag, zero4, 0, 0, 0);
        c1 = __builtin_amdgcn_mfma_f32_16x16x32_f16(tlo1, ifrag, c1, 0, 0, 0);
        half8 ah, al;
#pragma unroll
        for (int j = 0; j < 4; ++j) {
            ah[j] = (_Float16)c0[j];     al[j] = (_Float16)(c0[j] - (float)ah[j]);
            ah[4 + j] = (_Float16)c1[j]; al[4 + j] = (_Float16)(c1[j] - (float)ah[4 + j]);
        }
        *(half8*)(&sF[buf][0][((wid << 6) + lane) * 8]) = ah;
        *(half8*)(&sF[buf][1][((wid << 6) + lane) * 8]) = al;
    };
    auto r_phase = [&](int buf) {
        const half8 ahi = *(const half8*)(&sF[buf][0][((wid << 6) + lane) * 8]);
        const half8 alo = *(const half8*)(&sF[buf][1][((wid << 6) + lane) * 8]);
#pragma unroll
        for (int fj = 0; fj < 8; ++fj) {
            const half8 bhi = *(const half8*)(&sF[buf][0][((fj << 6) + lane) * 8]);
            const half8 blo = *(const half8*)(&sF[buf][1][((fj << 6) + lane) * 8]);
            acc[fj] = __builtin_amdgcn_mfma_f32_16x16x32_f16(ahi, bhi, acc[fj], 0, 0, 0);
            acc[fj] = __builtin_amdgcn_mfma_f32_16x16x32_f16(ahi, blo, acc[fj], 0, 0, 0);
            acc[fj] = __builtin_amdgcn_mfma_f32_16x16x32_f16(alo, bhi, acc[fj], 0, 0, 0);
        }
    };

    float4 tE[4], tO[4];
    g_issue(0, tE);
    w_phase(tE, 0);
    g_issue(32, tO);
    for (int c = 0; c < 32; c += 2) {
        barrier_lds_only();
        if (c + 2 < 32) g_issue((c + 2) * 32, tE);
        r_phase(0);
        w_phase(tO, 1);
        barrier_lds_only();
        if (c + 3 < 32) g_issue((c + 3) * 32, tO);
        r_phase(1);
        if (c + 2 < 32) w_phase(tE, 0);
    }

    float* gm = gpart + (size_t)n * Q * Q;
    const int m0 = (lane >> 4) * 4;
    const int nn = lane & 15;
#pragma unroll
    for (int fj = 0; fj < 8; ++fj) {
#pragma unroll
        for (int j = 0; j < 4; ++j) {
            gm[(size_t)(RB + m0 + j) * Q + fj * 16 + nn] = acc[fj][j];
        }
    }
}

// ---------------------------------------------------------------------------
// Kernel 2: Newton-Schulz (fp16 MFMA) + fused fp32-grade refinement.
// ---------------------------------------------------------------------------
__global__ __launch_bounds__(512) void ns_kernel(
    const float* __restrict__ gpart, int npart, float* __restrict__ Zg)
{
    __shared__ __align__(16) unsigned char pool[163840];
    Half4* bufA = (Half4*)pool;
    Half4* bufB = (Half4*)(pool + 32768);
    Half4* sZh  = (Half4*)(pool + 65536);
    Half4* bufC = (Half4*)(pool + 98304);
    Half4* bufD = (Half4*)(pool + 131072);
    float* sRow = (float*)pool;

    const int n = blockIdx.x;
    const int tid = threadIdx.x;
    const float* gp = gpart + (size_t)n * npart * Q * Q;

    float4 gv[8];
    float rsum[8];
#pragma unroll
    for (int t = 0; t < 8; ++t) {
        const int idx = tid + t * 512;
        float4 v = ((const float4*)gp)[idx];
        for (int pp = 1; pp < npart; ++pp) {
            const float4 w = ((const float4*)(gp + (size_t)pp * Q * Q))[idx];
            v.x += w.x; v.y += w.y; v.z += w.z; v.w += w.w;
        }
        gv[t] = v;
        rsum[t] = fabsf(v.x) + fabsf(v.y) + fabsf(v.z) + fabsf(v.w);
    }
#pragma unroll
    for (int t = 0; t < 8; ++t) {
#pragma unroll
        for (int off = 16; off > 0; off >>= 1)
            rsum[t] += __shfl_xor(rsum[t], off);
    }
    if ((tid & 31) == 0) {
#pragma unroll
        for (int t = 0; t < 8; ++t)
            sRow[(tid >> 5) + 16 * t] = rsum[t];
    }
    __syncthreads();
    float cmax = 0.0f;
#pragma unroll
    for (int i = 0; i < 4; ++i)
        cmax = fmaxf(cmax, sRow[(tid & 31) + 32 * i]);
#pragma unroll
    for (int off = 16; off > 0; off >>= 1)
        cmax = fmaxf(cmax, __shfl_xor(cmax, off));
    __syncthreads();
    const float c = cmax;
    const float rc = 1.0f / c;
    const float rs = 1.0f / sqrtf(c);

#pragma unroll
    for (int t = 0; t < 8; ++t) {
        const int idx = tid + t * 512;
        const int row = idx >> 5, c4 = idx & 31;
        const int slot = row * 32 + (c4 ^ (row & 15));
        float wv[4], zv[4];
        wv[0] = gv[t].x * rc; wv[1] = gv[t].y * rc;
        wv[2] = gv[t].z * rc; wv[3] = gv[t].w * rc;
        Half4 wh, wl, zh;
        _Float16* whp = (_Float16*)&wh;
        _Float16* wlp = (_Float16*)&wl;
        _Float16* zhp = (_Float16*)&zh;
#pragma unroll
        for (int j = 0; j < 4; ++j) {
            const _Float16 h = (_Float16)wv[j];
            whp[j] = h;
            wlp[j] = (_Float16)(wv[j] - (float)h);
            zv[j] = -0.5f * wv[j] + (((row >> 2) == c4 && (row & 3) == j) ? 1.5f : 0.0f);
            zhp[j] = (_Float16)zv[j];
        }
        bufA[slot] = wh;
        bufC[slot] = wh;
        bufD[slot] = wl;
        sZh[slot] = zh;
    }
    __syncthreads();

    const int lane = tid & 63;
    const int wid = tid >> 6;
    const int RB = wid * 16;
    const f32x4 zero4 = {0.0f, 0.0f, 0.0f, 0.0f};
    Half4* cur = bufA;
    Half4* scr = bufB;

    for (int it = 0; it < NS_LOOP; ++it) {
        f32x4 a1[8];
#pragma unroll
        for (int fj = 0; fj < 8; ++fj) a1[fj] = zero4;
#pragma unroll
        for (int kb = 0; kb < 4; ++kb) {
            const half8 af = frag_ld(cur, RB, kb * 8, lane);
#pragma unroll
            for (int fj = 0; fj < 8; ++fj) {
                const half8 bf = frag_ld(cur, fj * 16, kb * 8, lane);
                a1[fj] = __builtin_amdgcn_mfma_f32_16x16x32_f16(af, bf, a1[fj], 0, 0, 0);
            }
        }
#pragma unroll
        for (int fj = 0; fj < 8; ++fj) {
            const int p = cpos(RB, fj * 16, lane);
            cwrite(scr, p, 1.5f * cread(cur, p) - 0.5f * a1[fj]);
        }
        __syncthreads();

        f32x4 a2[8];
#pragma unroll
        for (int fj = 0; fj < 8; ++fj) a2[fj] = zero4;
#pragma unroll
        for (int kb = 0; kb < 4; ++kb) {
            const half8 af = frag_ld(scr, RB, kb * 8, lane);
#pragma unroll
            for (int fj = 0; fj < 8; ++fj) {
                const half8 bf = frag_ld(cur, fj * 16, kb * 8, lane);
                a2[fj] = __builtin_amdgcn_mfma_f32_16x16x32_f16(af, bf, a2[fj], 0, 0, 0);
            }
        }
        f32x4 wn[8];
#pragma unroll
        for (int fj = 0; fj < 8; ++fj) {
            const int p = cpos(RB, fj * 16, lane);
            wn[fj] = 1.5f * cread(scr, p) - 0.5f * a2[fj];
        }
        __syncthreads();
#pragma unroll
        for (int fj = 0; fj < 8; ++fj)
            cwrite(scr, cpos(RB, fj * 16, lane), wn[fj]);
        __syncthreads();

        f32x4 a3[8];
#pragma unroll
        for (int fj = 0; fj < 8; ++fj) a3[fj] = zero4;
#pragma unroll
        for (int kb = 0; kb < 4; ++kb) {
            const half8 af = frag_ld(scr, RB, kb * 8, lane);
#pragma unroll
            for (int fj = 0; fj < 8; ++fj) {
                const half8 bf = frag_ld(sZh, fj * 16, kb * 8, lane);
                a3[fj] = __builtin_amdgcn_mfma_f32_16x16x32_f16(af, bf, a3[fj], 0, 0, 0);
            }
        }
        f32x4 zn[8];
#pragma unroll
        for (int fj = 0; fj < 8; ++fj) {
            const int p = cpos(RB, fj * 16, lane);
            zn[fj] = 1.5f * cread(sZh, p) - 0.5f * a3[fj];
        }
        __syncthreads();
#pragma unroll
        for (int fj = 0; fj < 8; ++fj)
            cwrite(sZh, cpos(RB, fj * 16, lane), zn[fj]);
        __syncthreads();

        Half4* tmp = cur; cur = scr; scr = tmp;
    }

    // symmetrize z exactly
    {
        _Float16* zp = (_Float16*)sZh;
        for (int k = tid; k < Q * Q; k += 512) {
            const int r = k >> 7, cc = k & 127;
            if (r < cc) {
                const int i1 = (r * 32 + ((cc >> 2) ^ (r & 15))) * 4 + (cc & 3);
                const int i2 = (cc * 32 + ((r >> 2) ^ (cc & 15))) * 4 + (r & 3);
                const _Float16 av = (_Float16)(0.5f * ((float)zp[i1] + (float)zp[i2]));
                zp[i1] = av; zp[i2] = av;
            }
        }
    }
    __syncthreads();

    f32x4 racc[8];
#pragma unroll
    for (int fj = 0; fj < 8; ++fj) racc[fj] = zero4;
#pragma unroll
    for (int kb = 0; kb < 4; ++kb) {
        const half8 ah = frag_ld(bufC, RB, kb * 8, lane);
        const half8 al = frag_ld(bufD, RB, kb * 8, lane);
#pragma unroll
        for (int fj = 0; fj < 8; ++fj) {
            const half8 bz = frag_ld(sZh, fj * 16, kb * 8, lane);
            racc[fj] = __builtin_amdgcn_mfma_f32_16x16x32_f16(ah, bz, racc[fj], 0, 0, 0);
            racc[fj] = __builtin_amdgcn_mfma_f32_16x16x32_f16(al, bz, racc[fj], 0, 0, 0);
        }
    }
#pragma unroll
    for (int fj = 0; fj < 8; ++fj)
        cwrite_hl(bufA, bufB, cpos(RB, fj * 16, lane), racc[fj]);
    __syncthreads();

    f32x4 uacc[8];
#pragma unroll
    for (int fj = 0; fj < 8; ++fj) uacc[fj] = zero4;
#pragma unroll
    for (int kb = 0; kb < 4; ++kb) {
        const half8 az = frag_ld(sZh, RB, kb * 8, lane);
#pragma unroll
        for (int fj = 0; fj < 8; ++fj) {
            const half8 bz = frag_ld(sZh, fj * 16, kb * 8, lane);
            uacc[fj] = __builtin_amdgcn_mfma_f32_16x16x32_f16(az, bz, uacc[fj], 0, 0, 0);
        }
    }
#pragma unroll
    for (int fj = 0; fj < 8; ++fj)
        cwrite_hl(bufC, bufD, cpos(RB, fj * 16, lane), uacc[fj]);
    __syncthreads();

    f32x4 dacc[8];
#pragma unroll
    for (int fj = 0; fj < 8; ++fj) dacc[fj] = zero4;
#pragma unroll
    for (int kb = 0; kb < 4; ++kb) {
        const half8 rh = frag_ld(bufA, RB, kb * 8, lane);
        const half8 rl = frag_ld(bufB, RB, kb * 8, lane);
#pragma unroll
        for (int fj = 0; fj < 8; ++fj) {
            const half8 uh = frag_ld(bufC, fj * 16, kb * 8, lane);
            const half8 ul = frag_ld(bufD, fj * 16, kb * 8, lane);
            dacc[fj] = __builtin_amdgcn_mfma_f32_16x16x32_f16(rh, uh, dacc[fj], 0, 0, 0);
            dacc[fj] = __builtin_amdgcn_mfma_f32_16x16x32_f16(rh, ul, dacc[fj], 0, 0, 0);
            dacc[fj] = __builtin_amdgcn_mfma_f32_16x16x32_f16(rl, uh, dacc[fj], 0, 0, 0);
        }
    }

    float* zo = Zg + (size_t)n * Q * Q;
    const int m0 = (lane >> 4) * 4;
    const int nn = lane & 15;
#pragma unroll
    for (int fj = 0; fj < 8; ++fj) {
        const f32x4 zq = cread(sZh, cpos(RB, fj * 16, lane));
#pragma unroll
        for (int j = 0; j < 4; ++j) {
            zo[(size_t)(RB + m0 + j) * Q + fj * 16 + nn] =
                rs * (1.5f * zq[j] - 0.5f * dacc[fj][j]);
        }
    }
}

// ---------------------------------------------------------------------------
// Kernel 3: out[n] = temp[n] @ Zg[n], fp16 MFMA; tempH fast path.
// ---------------------------------------------------------------------------
__global__ __launch_bounds__(512) void apply_kernel(
    const float* __restrict__ X, const float* __restrict__ G,
    const float* __restrict__ lrp, const float* __restrict__ Zg,
    const _Float16* __restrict__ tempH, int use_th,
    float* __restrict__ out)
{
    __shared__ __align__(16) unsigned char pool[65536];
    Half4* sTh = (Half4*)pool;
    Half4* sZh = (Half4*)(pool + 32768);

    const int n = blockIdx.x >> 3;
    const int p0 = (blockIdx.x & 7) * 128;
    const int tid = threadIdx.x;
    const float* zb = Zg + (size_t)n * Q * Q;
    float* ob = out + (size_t)n * P * Q + (size_t)p0 * Q;

#pragma unroll
    for (int t = 0; t < 8; ++t) {
        const int idx = tid + t * 512;
        const int row = idx >> 5, c4 = idx & 31;
        const float4 v = ((const float4*)zb)[idx];
        Half4 h;
        h.x = (_Float16)v.x; h.y = (_Float16)v.y;
        h.z = (_Float16)v.z; h.w = (_Float16)v.w;
        sZh[row * 32 + (c4 ^ (row & 15))] = h;
    }

    if (use_th) {
        const _Float16* tb = tempH + ((size_t)n * P + p0) * Q;
#pragma unroll
        for (int t = 0; t < 4; ++t) {
            const int idx = tid + t * 512;
            const int row = idx >> 4, hg = idx & 15;
            const half8 hv = ((const half8*)tb)[idx];
            Half4 h1, h2;
            h1.x = hv[0]; h1.y = hv[1]; h1.z = hv[2]; h1.w = hv[3];
            h2.x = hv[4]; h2.y = hv[5]; h2.z = hv[6]; h2.w = hv[7];
            const int rx = row & 15;
            sTh[row * 32 + ((hg * 2) ^ rx)] = h1;
            sTh[row * 32 + ((hg * 2 + 1) ^ rx)] = h2;
        }
    } else {
        const float lr = *lrp;
        const float* xb = X + (size_t)n * P * Q + (size_t)p0 * Q;
        const float* gb = G + (size_t)n * P * Q + (size_t)p0 * Q;
#pragma unroll
        for (int t = 0; t < 8; ++t) {
            const int idx = tid + t * 512;
            const int row = idx >> 5, c4 = idx & 31;
            const float4 xv = ((const float4*)xb)[idx];
            const float4 gv = ((const float4*)gb)[idx];
            Half4 h;
            h.x = (_Float16)(xv.x - lr * gv.x);
            h.y = (_Float16)(xv.y - lr * gv.y);
            h.z = (_Float16)(xv.z - lr * gv.z);
            h.w = (_Float16)(xv.w - lr * gv.w);
            sTh[row * 32 + (c4 ^ (row & 15))] = h;
        }
    }
    __syncthreads();

    const int lane = tid & 63;
    const int wid = tid >> 6;
    const int RB = wid * 16;
    const f32x4 zero4 = {0.0f, 0.0f, 0.0f, 0.0f};

    f32x4 a[8];
#pragma unroll
    for (int fj = 0; fj < 8; ++fj) a[fj] = zero4;
#pragma unroll
    for (int kb = 0; kb < 4; ++kb) {
        const half8 af = frag_ld(sTh, RB, kb * 8, lane);
#pragma unroll
        for (int fj = 0; fj < 8; ++fj) {
            const half8 bf = frag_ld(sZh, fj * 16, kb * 8, lane);
            a[fj] = __builtin_amdgcn_mfma_f32_16x16x32_f16(af, bf, a[fj], 0, 0, 0);
        }
    }

    const int m0 = (lane >> 4) * 4;
    const int nn = lane & 15;
#pragma unroll
    for (int fj = 0; fj < 8; ++fj) {
#pragma unroll
        for (int j = 0; j < 4; ++j) {
            ob[(size_t)(RB + m0 + j) * Q + fj * 16 + nn] = a[fj][j];
        }
    }
}

extern "C" void kernel_launch(void* const* d_in, const int* in_sizes, int n_in,
                              void* d_out, int out_size, void* d_ws, size_t ws_size,
                              hipStream_t stream) {
    const float* X  = (const float*)d_in[0];
    const float* G  = (const float*)d_in[1];
    const float* lr = (const float*)d_in[2];
    float* outp = (float*)d_out;

    const size_t QQ = (size_t)Q * Q;
    const size_t mat = (size_t)NBATCH * QQ;
    const size_t thHalves = (size_t)NBATCH * P * Q;

    const size_t need_th = (1 + 4) * mat * sizeof(float) + thHalves * sizeof(_Float16);
    const int use_th = (ws_size >= need_th) ? 1 : 0;
    const int npart = use_th ? 4 : 1;

    float* Zg    = (float*)d_ws;
    float* gpart = Zg + mat;
    _Float16* tempH = use_th ? (_Float16*)(gpart + (size_t)4 * mat) : (_Float16*)0;

    if (use_th)
        gram_kernel4<<<NBATCH * 4, 512, 0, stream>>>(X, G, lr, gpart, tempH);
    else
        gram_kernel1<<<NBATCH, 512, 0, stream>>>(X, G, lr, gpart);
    ns_kernel<<<NBATCH, 512, 0, stream>>>(gpart, npart, Zg);
    apply_kernel<<<NBATCH * 8, 512, 0, stream>>>(X, G, lr, Zg, tempH, use_th, outp);
}

// Round 22
// 207.864 us; speedup vs baseline: 1.0321x; 1.0321x over previous
//
#include <hip/hip_runtime.h>

#define NBATCH 256
#define P 1024
#define Q 128
#define NS_LOOP 6

typedef _Float16 half8 __attribute__((ext_vector_type(8)));
typedef float f32x4 __attribute__((ext_vector_type(4)));
struct __attribute__((aligned(8))) Half4 { _Float16 x, y, z, w; };

// raw workgroup barrier: LDS visibility only, vmcnt floats across.
__device__ __forceinline__ void barrier_lds_only() {
    asm volatile("s_waitcnt lgkmcnt(0)" ::: "memory");
    __builtin_amdgcn_s_barrier();
    asm volatile("" ::: "memory");
}

// ---- swizzled fp16 machinery (counter-clean since r6) ----
__device__ __forceinline__ half8 frag_ld(const Half4* S, int rowbase, int slotbase, int lane) {
    const int r = rowbase + (lane & 15);
    const int g = (lane >> 4);
    const int rx = r & 15;
    const Half4 h1 = S[r * 32 + ((slotbase + g) ^ rx)];
    const Half4 h2 = S[r * 32 + ((slotbase + g + 4) ^ rx)];
    half8 v;
    v[0] = h1.x; v[1] = h1.y; v[2] = h1.z; v[3] = h1.w;
    v[4] = h2.x; v[5] = h2.y; v[6] = h2.z; v[7] = h2.w;
    return v;
}

__device__ __forceinline__ int cpos(int RB, int CB, int lane) {
    const int r = CB + (lane & 15);
    const int s = (RB >> 2) + (lane >> 4);
    return r * 32 + (s ^ (r & 15));
}

__device__ __forceinline__ f32x4 cread(const Half4* S, int p) {
    const Half4 h = S[p];
    f32x4 v;
    v[0] = (float)h.x; v[1] = (float)h.y; v[2] = (float)h.z; v[3] = (float)h.w;
    return v;
}

__device__ __forceinline__ void cwrite(Half4* S, int p, f32x4 v) {
    Half4 h;
    h.x = (_Float16)v[0]; h.y = (_Float16)v[1]; h.z = (_Float16)v[2]; h.w = (_Float16)v[3];
    S[p] = h;
}

__device__ __forceinline__ void cwrite_hl(Half4* Sh, Half4* Sl, int p, f32x4 v) {
    Half4 h, l;
    h.x = (_Float16)v[0]; h.y = (_Float16)v[1]; h.z = (_Float16)v[2]; h.w = (_Float16)v[3];
    l.x = (_Float16)(v[0] - (float)h.x);
    l.y = (_Float16)(v[1] - (float)h.y);
    l.z = (_Float16)(v[2] - (float)h.z);
    l.w = (_Float16)(v[3] - (float)h.w);
    Sh[p] = h; Sl[p] = l;
}

// ===========================================================================
// Kernel 1 (npart=4): gram, MFMA-identity transpose, 64-row chunks,
// 1 barrier/chunk (r21). r22: zero-init of fragment upper halves hoisted.
// ===========================================================================
__global__ __launch_bounds__(512) void gram_kernel4(
    const float* __restrict__ X, const float* __restrict__ G,
    const float* __restrict__ lrp, float* __restrict__ gpart,
    _Float16* __restrict__ tempH)
{
    __shared__ __align__(16) _Float16 sF[2][2][2][4096];  // 64KB

    const int n = blockIdx.x >> 2;
    const int part = blockIdx.x & 3;
    const float lr = *lrp;
    const float* xb = X + (size_t)n * P * Q;
    const float* gb = G + (size_t)n * P * Q;
    _Float16* th = tempH + (size_t)n * P * Q;

    const int tid = threadIdx.x;
    const int lane = tid & 63;
    const int wid = tid >> 6;
    const int rr = lane & 15;
    const int g = lane >> 4;
    const int RB = wid * 16;
    const int cq = wid * 4 + g;

    half8 ifrag;
#pragma unroll
    for (int j = 0; j < 8; ++j) ifrag[j] = (_Float16)0.0f;
#pragma unroll
    for (int j = 0; j < 4; ++j)
        if ((rr >> 2) == g && (rr & 3) == j) ifrag[j] = (_Float16)1.0f;

    const f32x4 zero4 = {0.0f, 0.0f, 0.0f, 0.0f};
    f32x4 acc[8];
#pragma unroll
    for (int fj = 0; fj < 8; ++fj) acc[fj] = zero4;

    const int ps = part * 256;

    // persistent fragment regs: upper halves stay zero (hoisted init)
    half8 thi0, tlo0, thi1, tlo1;
#pragma unroll
    for (int j = 0; j < 8; ++j) { thi0[j] = (_Float16)0.0f; tlo0[j] = (_Float16)0.0f;
                                  thi1[j] = (_Float16)0.0f; tlo1[j] = (_Float16)0.0f; }

    auto g_issue = [&](int pbase, float4* d) {
#pragma unroll
        for (int t = 0; t < 4; ++t) {
            d[2 * t]     = ((const float4*)(xb + (size_t)(pbase + 16 * t + rr) * Q))[cq];
            d[2 * t + 1] = ((const float4*)(gb + (size_t)(pbase + 16 * t + rr) * Q))[cq];
        }
    };
    auto w_half = [&](const float4* d, int buf, int win, int pbase) {
        const float t0[4] = {d[0].x - lr * d[1].x, d[0].y - lr * d[1].y,
                             d[0].z - lr * d[1].z, d[0].w - lr * d[1].w};
        const float t1[4] = {d[2].x - lr * d[3].x, d[2].y - lr * d[3].y,
                             d[2].z - lr * d[3].z, d[2].w - lr * d[3].w};
        Half4 h0, h1;
        h0.x = (_Float16)t0[0]; h0.y = (_Float16)t0[1];
        h0.z = (_Float16)t0[2]; h0.w = (_Float16)t0[3];
        h1.x = (_Float16)t1[0]; h1.y = (_Float16)t1[1];
        h1.z = (_Float16)t1[2]; h1.w = (_Float16)t1[3];
        *(Half4*)(th + (size_t)(pbase + rr) * Q + 4 * cq) = h0;
        *(Half4*)(th + (size_t)(pbase + 16 + rr) * Q + 4 * cq) = h1;
#pragma unroll
        for (int j = 0; j < 4; ++j) {
            thi0[j] = (_Float16)t0[j]; tlo0[j] = (_Float16)(t0[j] - (float)thi0[j]);
            thi1[j] = (_Float16)t1[j]; tlo1[j] = (_Float16)(t1[j] - (float)thi1[j]);
        }
        f32x4 c0 = __builtin_amdgcn_mfma_f32_16x16x32_f16(thi0, ifrag, zero4, 0, 0, 0);
        c0 = __builtin_amdgcn_mfma_f32_16x16x32_f16(tlo0, ifrag, c0, 0, 0, 0);
        f32x4 c1 = __builtin_amdgcn_mfma_f32_16x16x32_f16(thi1, ifrag, zero4, 0, 0, 0);
        c1 = __builtin_amdgcn_mfma_f32_16x16x32_f16(tlo1, ifrag, c1, 0, 0, 0);
        half8 ah, al;
#pragma unroll
        for (int j = 0; j < 4; ++j) {
            ah[j] = (_Float16)c0[j];     al[j] = (_Float16)(c0[j] - (float)ah[j]);
            ah[4 + j] = (_Float16)c1[j]; al[4 + j] = (_Float16)(c1[j] - (float)ah[4 + j]);
        }
        *(half8*)(&sF[buf][win][0][((wid << 6) + lane) * 8]) = ah;
        *(half8*)(&sF[buf][win][1][((wid << 6) + lane) * 8]) = al;
    };
    auto w_phase = [&](const float4* d, int buf, int pbase) {
        w_half(d, buf, 0, pbase);
        w_half(d + 4, buf, 1, pbase + 32);
    };
    auto r_phase = [&](int buf) {
#pragma unroll
        for (int win = 0; win < 2; ++win) {
            const half8 ahi = *(const half8*)(&sF[buf][win][0][((wid << 6) + lane) * 8]);
            const half8 alo = *(const half8*)(&sF[buf][win][1][((wid << 6) + lane) * 8]);
#pragma unroll
            for (int fj = 0; fj < 8; ++fj) {
                const half8 bhi = *(const half8*)(&sF[buf][win][0][((fj << 6) + lane) * 8]);
                const half8 blo = *(const half8*)(&sF[buf][win][1][((fj << 6) + lane) * 8]);
                acc[fj] = __builtin_amdgcn_mfma_f32_16x16x32_f16(ahi, bhi, acc[fj], 0, 0, 0);
                acc[fj] = __builtin_amdgcn_mfma_f32_16x16x32_f16(ahi, blo, acc[fj], 0, 0, 0);
                acc[fj] = __builtin_amdgcn_mfma_f32_16x16x32_f16(alo, bhi, acc[fj], 0, 0, 0);
            }
        }
    };

    float4 tE[8], tO[8];
    g_issue(ps + 0 * 64, tE);
    w_phase(tE, 0, ps + 0 * 64);
    g_issue(ps + 1 * 64, tO);

    barrier_lds_only();
    g_issue(ps + 2 * 64, tE);
    r_phase(0);
    w_phase(tO, 1, ps + 1 * 64);
    barrier_lds_only();
    g_issue(ps + 3 * 64, tO);
    r_phase(1);
    w_phase(tE, 0, ps + 2 * 64);
    barrier_lds_only();
    r_phase(0);
    w_phase(tO, 1, ps + 3 * 64);
    barrier_lds_only();
    r_phase(1);

    float* gm = gpart + ((size_t)n * 4 + part) * Q * Q;
    const int m0 = (lane >> 4) * 4;
    const int nn = lane & 15;
#pragma unroll
    for (int fj = 0; fj < 8; ++fj) {
#pragma unroll
        for (int j = 0; j < 4; ++j) {
            gm[(size_t)(RB + m0 + j) * Q + fj * 16 + nn] = acc[fj][j];
        }
    }
}

// ---- fallback gram (npart=1, no tempH) ----
__global__ __launch_bounds__(512) void gram_kernel1(
    const float* __restrict__ X, const float* __restrict__ G,
    const float* __restrict__ lrp, float* __restrict__ gpart)
{
    __shared__ __align__(16) _Float16 sF[2][2][4096];

    const int n = blockIdx.x;
    const float lr = *lrp;
    const float* xb = X + (size_t)n * P * Q;
    const float* gb = G + (size_t)n * P * Q;

    const int tid = threadIdx.x;
    const int lane = tid & 63;
    const int wid = tid >> 6;
    const int rr = lane & 15;
    const int g = lane >> 4;
    const int RB = wid * 16;
    const int cq = wid * 4 + g;

    half8 ifrag;
#pragma unroll
    for (int j = 0; j < 8; ++j) ifrag[j] = (_Float16)0.0f;
#pragma unroll
    for (int j = 0; j < 4; ++j)
        if ((rr >> 2) == g && (rr & 3) == j) ifrag[j] = (_Float16)1.0f;

    const f32x4 zero4 = {0.0f, 0.0f, 0.0f, 0.0f};
    f32x4 acc[8];
#pragma unroll
    for (int fj = 0; fj < 8; ++fj) acc[fj] = zero4;

    auto g_issue = [&](int pbase, float4* d) {
        d[0] = ((const float4*)(xb + (size_t)(pbase + rr) * Q))[cq];
        d[1] = ((const float4*)(gb + (size_t)(pbase + rr) * Q))[cq];
        d[2] = ((const float4*)(xb + (size_t)(pbase + 16 + rr) * Q))[cq];
        d[3] = ((const float4*)(gb + (size_t)(pbase + 16 + rr) * Q))[cq];
    };
    auto w_phase = [&](const float4* d, int buf) {
        const float t0[4] = {d[0].x - lr * d[1].x, d[0].y - lr * d[1].y,
                             d[0].z - lr * d[1].z, d[0].w - lr * d[1].w};
        const float t1[4] = {d[2].x - lr * d[3].x, d[2].y - lr * d[3].y,
                             d[2].z - lr * d[3].z, d[2].w - lr * d[3].w};
        half8 thi0, tlo0, thi1, tlo1;
#pragma unroll
        for (int j = 0; j < 8; ++j) { thi0[j] = (_Float16)0.0f; tlo0[j] = (_Float16)0.0f;
                                      thi1[j] = (_Float16)0.0f; tlo1[j] = (_Float16)0.0f; }
#pragma unroll
        for (int j = 0; j < 4; ++j) {
            thi0[j] = (_Float16)t0[j]; tlo0[j] = (_Float16)(t0[j] - (float)thi0[j]);
            thi1[j] = (_Float16)t1[j]; tlo1[j] = (_Float16)(t1[j] - (float)thi1[j]);
        }
        f32x4 c0 = __builtin_amdgcn_mfma_f32_16x16x32_f16(thi0, ifrag, zero4, 0, 0, 0);
        c0 = __builtin_amdgcn_mfma_f32_16x16x32_f16(tlo0, ifrag, c0, 0, 0, 0);
        f32x4 c1 = __builtin_amdgcn_mfma_f32_16x16x32_f16(thi1, ifrag, zero4, 0, 0, 0);
        c1 = __builtin_amdgcn_mfma_f32_16x16x32_f16(tlo1, ifrag, c1, 0, 0, 0);
        half8 ah, al;
#pragma unroll
        for (int j = 0; j < 4; ++j) {
            ah[j] = (_Float16)c0[j];     al[j] = (_Float16)(c0[j] - (float)ah[j]);
            ah[4 + j] = (_Float16)c1[j]; al[4 + j] = (_Float16)(c1[j] - (float)ah[4 + j]);
        }
        *(half8*)(&sF[buf][0][((wid << 6) + lane) * 8]) = ah;
        *(half8*)(&sF[buf][1][((wid << 6) + lane) * 8]) = al;
    };
    auto r_phase = [&](int buf) {
        const half8 ahi = *(const half8*)(&sF[buf][0][((wid << 6) + lane) * 8]);
        const half8 alo = *(const half8*)(&sF[buf][1][((wid << 6) + lane) * 8]);
#pragma unroll
        for (int fj = 0; fj < 8; ++fj) {
            const half8 bhi = *(const half8*)(&sF[buf][0][((fj << 6) + lane) * 8]);
            const half8 blo = *(const half8*)(&sF[buf][1][((fj << 6) + lane) * 8]);
            acc[fj] = __builtin_amdgcn_mfma_f32_16x16x32_f16(ahi, bhi, acc[fj], 0, 0, 0);
            acc[fj] = __builtin_amdgcn_mfma_f32_16x16x32_f16(ahi, blo, acc[fj], 0, 0, 0);
            acc[fj] = __builtin_amdgcn_mfma_f32_16x16x32_f16(alo, bhi, acc[fj], 0, 0, 0);
        }
    };

    float4 tE[4], tO[4];
    g_issue(0, tE);
    w_phase(tE, 0);
    g_issue(32, tO);
    for (int c = 0; c < 32; c += 2) {
        barrier_lds_only();
        if (c + 2 < 32) g_issue((c + 2) * 32, tE);
        r_phase(0);
        w_phase(tO, 1);
        barrier_lds_only();
        if (c + 3 < 32) g_issue((c + 3) * 32, tO);
        r_phase(1);
        if (c + 2 < 32) w_phase(tE, 0);
    }

    float* gm = gpart + (size_t)n * Q * Q;
    const int m0 = (lane >> 4) * 4;
    const int nn = lane & 15;
#pragma unroll
    for (int fj = 0; fj < 8; ++fj) {
#pragma unroll
        for (int j = 0; j < 4; ++j) {
            gm[(size_t)(RB + m0 + j) * Q + fj * 16 + nn] = acc[fj][j];
        }
    }
}

// ---------------------------------------------------------------------------
// Kernel 2: Newton-Schulz (fp16 MFMA) + fused fp32-grade refinement.
// r22: writes Zh (fp16 row-major) instead of fp32 Zg — apply only ever
// needs fp16; single cast at the source (identical rounding path).
// ---------------------------------------------------------------------------
__global__ __launch_bounds__(512) void ns_kernel(
    const float* __restrict__ gpart, int npart, _Float16* __restrict__ Zh)
{
    __shared__ __align__(16) unsigned char pool[163840];
    Half4* bufA = (Half4*)pool;
    Half4* bufB = (Half4*)(pool + 32768);
    Half4* sZh  = (Half4*)(pool + 65536);
    Half4* bufC = (Half4*)(pool + 98304);
    Half4* bufD = (Half4*)(pool + 131072);
    float* sRow = (float*)pool;

    const int n = blockIdx.x;
    const int tid = threadIdx.x;
    const float* gp = gpart + (size_t)n * npart * Q * Q;

    float4 gv[8];
    float rsum[8];
#pragma unroll
    for (int t = 0; t < 8; ++t) {
        const int idx = tid + t * 512;
        float4 v = ((const float4*)gp)[idx];
        for (int pp = 1; pp < npart; ++pp) {
            const float4 w = ((const float4*)(gp + (size_t)pp * Q * Q))[idx];
            v.x += w.x; v.y += w.y; v.z += w.z; v.w += w.w;
        }
        gv[t] = v;
        rsum[t] = fabsf(v.x) + fabsf(v.y) + fabsf(v.z) + fabsf(v.w);
    }
#pragma unroll
    for (int t = 0; t < 8; ++t) {
#pragma unroll
        for (int off = 16; off > 0; off >>= 1)
            rsum[t] += __shfl_xor(rsum[t], off);
    }
    if ((tid & 31) == 0) {
#pragma unroll
        for (int t = 0; t < 8; ++t)
            sRow[(tid >> 5) + 16 * t] = rsum[t];
    }
    __syncthreads();
    float cmax = 0.0f;
#pragma unroll
    for (int i = 0; i < 4; ++i)
        cmax = fmaxf(cmax, sRow[(tid & 31) + 32 * i]);
#pragma unroll
    for (int off = 16; off > 0; off >>= 1)
        cmax = fmaxf(cmax, __shfl_xor(cmax, off));
    __syncthreads();
    const float c = cmax;
    const float rc = 1.0f / c;
    const float rs = 1.0f / sqrtf(c);

#pragma unroll
    for (int t = 0; t < 8; ++t) {
        const int idx = tid + t * 512;
        const int row = idx >> 5, c4 = idx & 31;
        const int slot = row * 32 + (c4 ^ (row & 15));
        float wv[4], zv[4];
        wv[0] = gv[t].x * rc; wv[1] = gv[t].y * rc;
        wv[2] = gv[t].z * rc; wv[3] = gv[t].w * rc;
        Half4 wh, wl, zh;
        _Float16* whp = (_Float16*)&wh;
        _Float16* wlp = (_Float16*)&wl;
        _Float16* zhp = (_Float16*)&zh;
#pragma unroll
        for (int j = 0; j < 4; ++j) {
            const _Float16 h = (_Float16)wv[j];
            whp[j] = h;
            wlp[j] = (_Float16)(wv[j] - (float)h);
            zv[j] = -0.5f * wv[j] + (((row >> 2) == c4 && (row & 3) == j) ? 1.5f : 0.0f);
            zhp[j] = (_Float16)zv[j];
        }
        bufA[slot] = wh;
        bufC[slot] = wh;
        bufD[slot] = wl;
        sZh[slot] = zh;
    }
    __syncthreads();

    const int lane = tid & 63;
    const int wid = tid >> 6;
    const int RB = wid * 16;
    const f32x4 zero4 = {0.0f, 0.0f, 0.0f, 0.0f};
    Half4* cur = bufA;
    Half4* scr = bufB;

    for (int it = 0; it < NS_LOOP; ++it) {
        f32x4 a1[8];
#pragma unroll
        for (int fj = 0; fj < 8; ++fj) a1[fj] = zero4;
#pragma unroll
        for (int kb = 0; kb < 4; ++kb) {
            const half8 af = frag_ld(cur, RB, kb * 8, lane);
#pragma unroll
            for (int fj = 0; fj < 8; ++fj) {
                const half8 bf = frag_ld(cur, fj * 16, kb * 8, lane);
                a1[fj] = __builtin_amdgcn_mfma_f32_16x16x32_f16(af, bf, a1[fj], 0, 0, 0);
            }
        }
#pragma unroll
        for (int fj = 0; fj < 8; ++fj) {
            const int p = cpos(RB, fj * 16, lane);
            cwrite(scr, p, 1.5f * cread(cur, p) - 0.5f * a1[fj]);
        }
        __syncthreads();

        f32x4 a2[8];
#pragma unroll
        for (int fj = 0; fj < 8; ++fj) a2[fj] = zero4;
#pragma unroll
        for (int kb = 0; kb < 4; ++kb) {
            const half8 af = frag_ld(scr, RB, kb * 8, lane);
#pragma unroll
            for (int fj = 0; fj < 8; ++fj) {
                const half8 bf = frag_ld(cur, fj * 16, kb * 8, lane);
                a2[fj] = __builtin_amdgcn_mfma_f32_16x16x32_f16(af, bf, a2[fj], 0, 0, 0);
            }
        }
        f32x4 wn[8];
#pragma unroll
        for (int fj = 0; fj < 8; ++fj) {
            const int p = cpos(RB, fj * 16, lane);
            wn[fj] = 1.5f * cread(scr, p) - 0.5f * a2[fj];
        }
        __syncthreads();
#pragma unroll
        for (int fj = 0; fj < 8; ++fj)
            cwrite(scr, cpos(RB, fj * 16, lane), wn[fj]);
        __syncthreads();

        f32x4 a3[8];
#pragma unroll
        for (int fj = 0; fj < 8; ++fj) a3[fj] = zero4;
#pragma unroll
        for (int kb = 0; kb < 4; ++kb) {
            const half8 af = frag_ld(scr, RB, kb * 8, lane);
#pragma unroll
            for (int fj = 0; fj < 8; ++fj) {
                const half8 bf = frag_ld(sZh, fj * 16, kb * 8, lane);
                a3[fj] = __builtin_amdgcn_mfma_f32_16x16x32_f16(af, bf, a3[fj], 0, 0, 0);
            }
        }
        f32x4 zn[8];
#pragma unroll
        for (int fj = 0; fj < 8; ++fj) {
            const int p = cpos(RB, fj * 16, lane);
            zn[fj] = 1.5f * cread(sZh, p) - 0.5f * a3[fj];
        }
        __syncthreads();
#pragma unroll
        for (int fj = 0; fj < 8; ++fj)
            cwrite(sZh, cpos(RB, fj * 16, lane), zn[fj]);
        __syncthreads();

        Half4* tmp = cur; cur = scr; scr = tmp;
    }

    // symmetrize z exactly
    {
        _Float16* zp = (_Float16*)sZh;
        for (int k = tid; k < Q * Q; k += 512) {
            const int r = k >> 7, cc = k & 127;
            if (r < cc) {
                const int i1 = (r * 32 + ((cc >> 2) ^ (r & 15))) * 4 + (cc & 3);
                const int i2 = (cc * 32 + ((r >> 2) ^ (cc & 15))) * 4 + (r & 3);
                const _Float16 av = (_Float16)(0.5f * ((float)zp[i1] + (float)zp[i2]));
                zp[i1] = av; zp[i2] = av;
            }
        }
    }
    __syncthreads();

    f32x4 racc[8];
#pragma unroll
    for (int fj = 0; fj < 8; ++fj) racc[fj] = zero4;
#pragma unroll
    for (int kb = 0; kb < 4; ++kb) {
        const half8 ah = frag_ld(bufC, RB, kb * 8, lane);
        const half8 al = frag_ld(bufD, RB, kb * 8, lane);
#pragma unroll
        for (int fj = 0; fj < 8; ++fj) {
            const half8 bz = frag_ld(sZh, fj * 16, kb * 8, lane);
            racc[fj] = __builtin_amdgcn_mfma_f32_16x16x32_f16(ah, bz, racc[fj], 0, 0, 0);
            racc[fj] = __builtin_amdgcn_mfma_f32_16x16x32_f16(al, bz, racc[fj], 0, 0, 0);
        }
    }
#pragma unroll
    for (int fj = 0; fj < 8; ++fj)
        cwrite_hl(bufA, bufB, cpos(RB, fj * 16, lane), racc[fj]);
    __syncthreads();

    f32x4 uacc[8];
#pragma unroll
    for (int fj = 0; fj < 8; ++fj) uacc[fj] = zero4;
#pragma unroll
    for (int kb = 0; kb < 4; ++kb) {
        const half8 az = frag_ld(sZh, RB, kb * 8, lane);
#pragma unroll
        for (int fj = 0; fj < 8; ++fj) {
            const half8 bz = frag_ld(sZh, fj * 16, kb * 8, lane);
            uacc[fj] = __builtin_amdgcn_mfma_f32_16x16x32_f16(az, bz, uacc[fj], 0, 0, 0);
        }
    }
#pragma unroll
    for (int fj = 0; fj < 8; ++fj)
        cwrite_hl(bufC, bufD, cpos(RB, fj * 16, lane), uacc[fj]);
    __syncthreads();

    f32x4 dacc[8];
#pragma unroll
    for (int fj = 0; fj < 8; ++fj) dacc[fj] = zero4;
#pragma unroll
    for (int kb = 0; kb < 4; ++kb) {
        const half8 rh = frag_ld(bufA, RB, kb * 8, lane);
        const half8 rl = frag_ld(bufB, RB, kb * 8, lane);
#pragma unroll
        for (int fj = 0; fj < 8; ++fj) {
            const half8 uh = frag_ld(bufC, fj * 16, kb * 8, lane);
            const half8 ul = frag_ld(bufD, fj * 16, kb * 8, lane);
            dacc[fj] = __builtin_amdgcn_mfma_f32_16x16x32_f16(rh, uh, dacc[fj], 0, 0, 0);
            dacc[fj] = __builtin_amdgcn_mfma_f32_16x16x32_f16(rh, ul, dacc[fj], 0, 0, 0);
            dacc[fj] = __builtin_amdgcn_mfma_f32_16x16x32_f16(rl, uh, dacc[fj], 0, 0, 0);
        }
    }

    _Float16* zo = Zh + (size_t)n * Q * Q;
    const int m0 = (lane >> 4) * 4;
    const int nn = lane & 15;
#pragma unroll
    for (int fj = 0; fj < 8; ++fj) {
        const f32x4 zq = cread(sZh, cpos(RB, fj * 16, lane));
#pragma unroll
        for (int j = 0; j < 4; ++j) {
            zo[(size_t)(RB + m0 + j) * Q + fj * 16 + nn] =
                (_Float16)(rs * (1.5f * zq[j] - 0.5f * dacc[fj][j]));
        }
    }
}

// ---------------------------------------------------------------------------
// Kernel 3: out[n] = temp[n] @ Zh[n], fp16 MFMA. Zh staged via the proven
// tempH half8->swizzle path (no fp32->fp16 cvt, half the staging bytes).
// ---------------------------------------------------------------------------
__global__ __launch_bounds__(512) void apply_kernel(
    const float* __restrict__ X, const float* __restrict__ G,
    const float* __restrict__ lrp, const _Float16* __restrict__ Zh,
    const _Float16* __restrict__ tempH, int use_th,
    float* __restrict__ out)
{
    __shared__ __align__(16) unsigned char pool[65536];
    Half4* sTh = (Half4*)pool;
    Half4* sZh = (Half4*)(pool + 32768);

    const int n = blockIdx.x >> 3;
    const int p0 = (blockIdx.x & 7) * 128;
    const int tid = threadIdx.x;
    float* ob = out + (size_t)n * P * Q + (size_t)p0 * Q;

    // stage Zh (fp16 row-major) -> swizzled LDS
    {
        const _Float16* zb = Zh + (size_t)n * Q * Q;
#pragma unroll
        for (int t = 0; t < 4; ++t) {
            const int idx = tid + t * 512;
            const int row = idx >> 4, hg = idx & 15;
            const half8 hv = ((const half8*)zb)[idx];
            Half4 h1, h2;
            h1.x = hv[0]; h1.y = hv[1]; h1.z = hv[2]; h1.w = hv[3];
            h2.x = hv[4]; h2.y = hv[5]; h2.z = hv[6]; h2.w = hv[7];
            const int rx = row & 15;
            sZh[row * 32 + ((hg * 2) ^ rx)] = h1;
            sZh[row * 32 + ((hg * 2 + 1) ^ rx)] = h2;
        }
    }

    if (use_th) {
        const _Float16* tb = tempH + ((size_t)n * P + p0) * Q;
#pragma unroll
        for (int t = 0; t < 4; ++t) {
            const int idx = tid + t * 512;
            const int row = idx >> 4, hg = idx & 15;
            const half8 hv = ((const half8*)tb)[idx];
            Half4 h1, h2;
            h1.x = hv[0]; h1.y = hv[1]; h1.z = hv[2]; h1.w = hv[3];
            h2.x = hv[4]; h2.y = hv[5]; h2.z = hv[6]; h2.w = hv[7];
            const int rx = row & 15;
            sTh[row * 32 + ((hg * 2) ^ rx)] = h1;
            sTh[row * 32 + ((hg * 2 + 1) ^ rx)] = h2;
        }
    } else {
        const float lr = *lrp;
        const float* xb = X + (size_t)n * P * Q + (size_t)p0 * Q;
        const float* gb = G + (size_t)n * P * Q + (size_t)p0 * Q;
#pragma unroll
        for (int t = 0; t < 8; ++t) {
            const int idx = tid + t * 512;
            const int row = idx >> 5, c4 = idx & 31;
            const float4 xv = ((const float4*)xb)[idx];
            const float4 gv = ((const float4*)gb)[idx];
            Half4 h;
            h.x = (_Float16)(xv.x - lr * gv.x);
            h.y = (_Float16)(xv.y - lr * gv.y);
            h.z = (_Float16)(xv.z - lr * gv.z);
            h.w = (_Float16)(xv.w - lr * gv.w);
            sTh[row * 32 + (c4 ^ (row & 15))] = h;
        }
    }
    __syncthreads();

    const int lane = tid & 63;
    const int wid = tid >> 6;
    const int RB = wid * 16;
    const f32x4 zero4 = {0.0f, 0.0f, 0.0f, 0.0f};

    f32x4 a[8];
#pragma unroll
    for (int fj = 0; fj < 8; ++fj) a[fj] = zero4;
#pragma unroll
    for (int kb = 0; kb < 4; ++kb) {
        const half8 af = frag_ld(sTh, RB, kb * 8, lane);
#pragma unroll
        for (int fj = 0; fj < 8; ++fj) {
            const half8 bf = frag_ld(sZh, fj * 16, kb * 8, lane);
            a[fj] = __builtin_amdgcn_mfma_f32_16x16x32_f16(af, bf, a[fj], 0, 0, 0);
        }
    }

    const int m0 = (lane >> 4) * 4;
    const int nn = lane & 15;
#pragma unroll
    for (int fj = 0; fj < 8; ++fj) {
#pragma unroll
        for (int j = 0; j < 4; ++j) {
            ob[(size_t)(RB + m0 + j) * Q + fj * 16 + nn] = a[fj][j];
        }
    }
}

extern "C" void kernel_launch(void* const* d_in, const int* in_sizes, int n_in,
                              void* d_out, int out_size, void* d_ws, size_t ws_size,
                              hipStream_t stream) {
    const float* X  = (const float*)d_in[0];
    const float* G  = (const float*)d_in[1];
    const float* lr = (const float*)d_in[2];
    float* outp = (float*)d_out;

    const size_t QQ = (size_t)Q * Q;
    const size_t mat = (size_t)NBATCH * QQ;            // floats
    const size_t thHalves = (size_t)NBATCH * P * Q;

    // ws: [Zh fp16][gpart fp32 x npart][tempH fp16]
    const size_t zhBytes = mat * sizeof(_Float16);
    const size_t need_th = zhBytes + 4 * mat * sizeof(float) + thHalves * sizeof(_Float16);
    const size_t need_1  = zhBytes + 1 * mat * sizeof(float);
    const int use_th = (ws_size >= need_th) ? 1 : 0;
    const int npart = use_th ? 4 : 1;
    (void)need_1;

    _Float16* Zh   = (_Float16*)d_ws;
    float* gpart   = (float*)((char*)d_ws + zhBytes);
    _Float16* tempH = use_th ? (_Float16*)(gpart + (size_t)4 * mat) : (_Float16*)0;

    if (use_th)
        gram_kernel4<<<NBATCH * 4, 512, 0, stream>>>(X, G, lr, gpart, tempH);
    else
        gram_kernel1<<<NBATCH, 512, 0, stream>>>(X, G, lr, gpart);
    ns_kernel<<<NBATCH, 512, 0, stream>>>(gpart, npart, Zh);
    apply_kernel<<<NBATCH * 8, 512, 0, stream>>>(X, G, lr, Zh, tempH, use_th, outp);
}